// Round 14
// baseline (274.193 us; speedup 1.0000x reference)
//
#include <hip/hip_runtime.h>

// SNN loss, MI355X. Round 14: R13 (best, 83.1us) with k_prep folded into
// k_norm via last-block device-scope reduction (threadfence + ws counter,
// counter/out zeroed by hipMemsetAsync per call). 3 kernels instead of 4.
// k_main and k_rows are UNCHANGED from R13.
//  k_norm: raw x -> bf16 (ws), per-row sqn + sum (fp32); last block reduces
//          row sums in fp64 -> inv_std (scal)
//  k_main: upper-tri 128x128 MFMA tiles of x.x^T (2080 blocks), tbuf 48KB,
//          counted vmcnt(8/4/0), granule swizzle, shared-tile-max epilogue
//  k_rows: combine partials per row, block atomicAdd of -mean into out

#define NROW 8192
#define NDIM 512
#define BM   128
#define BK   32
#define NKT  (NDIM / BK)           // 16 K-tiles
#define NT   (NROW / BM)           // 64 tiles per dim
#define NBLK (NT * (NT + 1) / 2)   // 2080 upper-tri blocks
#define TILE (BM * BK)             // 4096 elements

typedef __attribute__((ext_vector_type(8))) short bf16x8;
typedef __attribute__((ext_vector_type(4))) float f32x4;

#define NEG_INF (-__builtin_inff())

// ---- workspace layout (bytes) ----
static const size_t WS_CNT  = 0;                                   // u32 counter
static const size_t WS_SCAL = 4096;                                // inv_std float
static const size_t WS_XB   = 8192;                                // bf16 x: 8M
static const size_t WS_SQN  = WS_XB + (size_t)NROW * NDIM * 2;     // 8192 f32
static const size_t WS_RS   = WS_SQN + (size_t)NROW * 4;           // 8192 f32 row sums
static const size_t WS_P4   = WS_RS + (size_t)NROW * 4;            // 64*8192 float4

__device__ __forceinline__ unsigned short f2bf(float f) {
    unsigned int u = __float_as_uint(f);      // finite inputs only
    u += 0x7FFFu + ((u >> 16) & 1u);          // round-to-nearest-even
    return (unsigned short)(u >> 16);
}

#define GLD_LDS16(gp, lp) __builtin_amdgcn_global_load_lds( \
    (const __attribute__((address_space(1))) unsigned int*)(gp), \
    (__attribute__((address_space(3))) unsigned int*)(lp), 16, 0, 0)

// ------- raw x -> bf16 + row sqn/sum; last block -> inv_std (fused k_prep) -------
__global__ __launch_bounds__(256) void k_norm(const float* __restrict__ x,
                                              unsigned short* __restrict__ xb,
                                              float* __restrict__ sqn,
                                              float* __restrict__ rsum,
                                              unsigned int* __restrict__ counter,
                                              float* __restrict__ scal) {
    int w = threadIdx.x >> 6, lane = threadIdx.x & 63;
    int row = blockIdx.x * 4 + w;
    const float4* xr = (const float4*)(x + (size_t)row * NDIM);
    ushort4* xo = (ushort4*)(xb + (size_t)row * NDIM);
    float ss = 0.f, s1 = 0.f;
#pragma unroll
    for (int ph = 0; ph < 2; ++ph) {
        float4 v = xr[ph * 64 + lane];
        ss += v.x * v.x + v.y * v.y + v.z * v.z + v.w * v.w;
        s1 += (v.x + v.y) + (v.z + v.w);
        xo[ph * 64 + lane] = make_ushort4(f2bf(v.x), f2bf(v.y), f2bf(v.z), f2bf(v.w));
    }
#pragma unroll
    for (int off = 32; off >= 1; off >>= 1) {
        ss += __shfl_xor(ss, off, 64);
        s1 += __shfl_xor(s1, off, 64);
    }
    if (lane == 0) { sqn[row] = ss; rsum[row] = s1; }

    // ---- fused k_prep: last arriving block computes inv_std ----
    __threadfence();                               // my writes -> device scope
    __syncthreads();
    __shared__ unsigned int ticket;
    if (threadIdx.x == 0) ticket = atomicAdd(counter, 1u);
    __syncthreads();
    if (ticket == gridDim.x - 1) {
        __threadfence();                           // acquire all blocks' writes
        int t = threadIdx.x;
        double s = 0.0, q = 0.0;
        for (int i = t; i < NROW; i += 256) { s += (double)rsum[i]; q += (double)sqn[i]; }
#pragma unroll
        for (int off = 32; off >= 1; off >>= 1) {
            s += __shfl_xor(s, off, 64);
            q += __shfl_xor(q, off, 64);
        }
        __shared__ double sa[4], sb[4];
        if ((t & 63) == 0) { sa[t >> 6] = s; sb[t >> 6] = q; }
        __syncthreads();
        if (t == 0) {
            double S = sa[0] + sa[1] + sa[2] + sa[3];
            double SS = sb[0] + sb[1] + sb[2] + sb[3];
            const double N = (double)NROW * (double)NDIM;
            double var = (SS - S * S / N) / (N - 1.0);   // ddof=1
            scal[0] = (float)(1.0 / sqrt(var));          // inv_std
        }
    }
}

// ---------------- main: upper-tri GEMM + dual-sided fused LSE ----------------
__global__ __launch_bounds__(256, 3) void k_main(const unsigned short* __restrict__ xb,
                                                 const float* __restrict__ sqn,
                                                 const int* __restrict__ y,
                                                 const float* __restrict__ Tp,
                                                 const float* __restrict__ scal,
                                                 float4* __restrict__ part) {
    // 48 KB: [buf3][A|B][128*32 bf16], granule-swizzled. Epilogue overlays:
    //   P  (float2[2 wr][2 wc][16 qq][64 rows]) at 0      (32 KB)
    //   redC (float2[128][2 wr])                at 32 KB  ( 2 KB)
    //   mxw (float[4])                          at 34 KB
    __shared__ __attribute__((aligned(16))) unsigned short lds[3][2][TILE];
    float2* P    = (float2*)&lds[0][0][0];
    float2* redC = (float2*)((char*)&lds[0][0][0] + 32768);
    float*  mxw  = (float*)((char*)&lds[0][0][0] + 34816);

    // XCD chunking (2080 = 8*260) over SUPERTILE-ordered triangle cells
    // (8x8 supertiles -> resident blocks per XCD share ~2MB of panels in L2).
    int bid = blockIdx.x;
    int L = (bid & 7) * (NBLK / 8) + (bid >> 3);
    int RT = 0;
    for (;;) { int cnt = 36 + 64 * (7 - RT); if (L < cnt) break; L -= cnt; ++RT; }
    int rt, ct;
    if (L < 36) {                    // diagonal supertile: triangular cells
        int i = 0;
        while (L >= 8 - i) { L -= 8 - i; ++i; }
        rt = RT * 8 + i; ct = RT * 8 + i + L;
    } else {                         // off-diagonal supertile: full 8x8
        L -= 36;
        int CT = RT + 1 + (L >> 6), cc = L & 63;
        rt = RT * 8 + (cc >> 3); ct = CT * 8 + (cc & 7);
    }
    const bool diag = (rt == ct);

    const int tid = threadIdx.x;
    const int w = tid >> 6, lane = tid & 63;
    const int wr = w >> 1, wc = w & 1;           // 2x2 waves, 64x64 each
    const int g = lane >> 4, qq = lane & 15;
    const int rowTile = rt * BM, colTile = ct * BM;

    // staging coords: chunk q covers rows [q*16,q*16+16); lane -> row q*16+(l>>2),
    // SOURCE granule pre-swizzled: (l&3)^((l>>3)&3) == (row>>1)&3 within chunk.
    const int q0 = w * 2, q1 = w * 2 + 1;
    const int colg = ((lane & 3) ^ ((lane >> 3) & 3)) * 8;
    const int sr = lane >> 2;
    const unsigned short* gA0 = xb + (size_t)(rowTile + q0 * 16 + sr) * NDIM + colg;
    const unsigned short* gA1 = xb + (size_t)(rowTile + q1 * 16 + sr) * NDIM + colg;
    const unsigned short* gB0 = xb + (size_t)(colTile + q0 * 16 + sr) * NDIM + colg;
    const unsigned short* gB1 = xb + (size_t)(colTile + q1 * 16 + sr) * NDIM + colg;

#define STAGE_T(buf, ke) do { \
    GLD_LDS16(gA0 + (ke), &lds[buf][0][q0 * 512]); \
    GLD_LDS16(gA1 + (ke), &lds[buf][0][q1 * 512]); \
    GLD_LDS16(gB0 + (ke), &lds[buf][1][q0 * 512]); \
    GLD_LDS16(gB1 + (ke), &lds[buf][1][q1 * 512]); } while (0)

    // swizzled read offset: granule g of row r sits at g^((r>>1)&3)
    const int kx = (g ^ ((qq >> 1) & 3)) * 8;
    const int aoff = (wr * 64 + qq) * BK + kx;     // + mi*16*BK
    const int boff = (wc * 64 + qq) * BK + kx;     // + ni*16*BK

    f32x4 acc[4][4];
    const f32x4 zero = {0.f, 0.f, 0.f, 0.f};
#pragma unroll
    for (int i = 0; i < 4; ++i)
#pragma unroll
        for (int j = 0; j < 4; ++j) acc[i][j] = zero;

    // prologue: tiles 0,1 in flight (diag stages B too: pointers coincide)
    STAGE_T(0, 0);
    STAGE_T(1, BK);

    int c = 0;
    for (int kt = 0; kt < NKT; ++kt) {
        if (kt + 2 < NKT) {
            int sb = c + 2; if (sb >= 3) sb -= 3;
            STAGE_T(sb, (kt + 2) * BK);
            asm volatile("s_waitcnt vmcnt(8)" ::: "memory");  // tile kt landed
        } else if (kt + 1 < NKT) {
            asm volatile("s_waitcnt vmcnt(4)" ::: "memory");
        } else {
            asm volatile("s_waitcnt vmcnt(0)" ::: "memory");
        }
        __builtin_amdgcn_s_barrier();                         // publish tile kt

        const unsigned short* AA = &lds[c][0][0];
        const unsigned short* BB = &lds[c][1][0];
        bf16x8 af[4], bfr[4];
#pragma unroll
        for (int mi = 0; mi < 4; ++mi)
            af[mi] = *(const bf16x8*)&AA[aoff + mi * 16 * BK];
#pragma unroll
        for (int ni = 0; ni < 4; ++ni)
            bfr[ni] = *(const bf16x8*)&BB[boff + ni * 16 * BK];
        __builtin_amdgcn_s_setprio(1);
#pragma unroll
        for (int mi = 0; mi < 4; ++mi)
#pragma unroll
            for (int ni = 0; ni < 4; ++ni)
                acc[mi][ni] = __builtin_amdgcn_mfma_f32_16x16x32_bf16(
                    af[mi], bfr[ni], acc[mi][ni], 0, 0, 0);
        __builtin_amdgcn_s_setprio(0);
        asm volatile("s_waitcnt lgkmcnt(0)" ::: "memory");    // my reads retired
        __builtin_amdgcn_s_barrier();                         // release buf c
        c += 1; if (c == 3) c = 0;
    }

    // ---- epilogue (shared tile-max) ----
    const float c2 = scal[0] * __builtin_amdgcn_exp2f(Tp[0] * 3.321928094887362f)
                             * 1.4426950408889634f;   // inv_std * 10^T * log2e
    float scol[4]; int ycol[4];
#pragma unroll
    for (int ni = 0; ni < 4; ++ni) {
        int C = colTile + wc * 64 + ni * 16 + qq;
        scol[ni] = sqn[C];
        ycol[ni] = y[C];
    }

    // pass A: acc := s2 in place; bits -> mm0/mm1; thread-local max
    unsigned mm0 = 0, mm1 = 0;
    float tmax = NEG_INF;
#pragma unroll
    for (int mi = 0; mi < 4; ++mi) {
        float srow4[4]; int yrow4[4];
#pragma unroll
        for (int r = 0; r < 4; ++r) {
            int R = rowTile + wr * 64 + mi * 16 + g * 4 + r;
            srow4[r] = sqn[R];
            yrow4[r] = y[R];
        }
#pragma unroll
        for (int r = 0; r < 4; ++r) {
            const int R = rowTile + wr * 64 + mi * 16 + g * 4 + r;
#pragma unroll
            for (int ni = 0; ni < 4; ++ni) {
                const int C = colTile + wc * 64 + ni * 16 + qq;
                float sq = fmaf(-2.f, acc[mi][ni][r], srow4[r] + scol[ni]);
                sq = fmaxf(sq, 0.f);
                float s2 = -__builtin_amdgcn_sqrtf(sq) * c2;
                if (R == C) s2 = NEG_INF;          // diagonal mask
                acc[mi][ni][r] = s2;
                tmax = fmaxf(tmax, s2);
                unsigned bit = (yrow4[r] == ycol[ni]) ? 1u : 0u;
                int idx = ((mi & 1) * 4 + r) * 4 + ni;
                if (mi < 2) mm0 |= bit << idx; else mm1 |= bit << idx;
            }
        }
    }
    // block-wide tile max Mt
#pragma unroll
    for (int off = 1; off <= 32; off <<= 1) tmax = fmaxf(tmax, __shfl_xor(tmax, off, 64));
    if (lane == 0) mxw[w] = tmax;
    __syncthreads();                               // barrier 1 (staging long dead)
    const float Mt = fmaxf(fmaxf(mxw[0], mxw[1]), fmaxf(mxw[2], mxw[3]));

    // pass B: acc := exp2(s2 - Mt); row partials -> P (float2, XOR swizzle);
    // col partials -> redC. All partials share Mt: merges are pure adds.
#pragma unroll
    for (int mi = 0; mi < 4; ++mi) {
        unsigned mmw = (mi < 2) ? mm0 : mm1;
#pragma unroll
        for (int r = 0; r < 4; ++r) {
            float ld = 0.f, ln = 0.f;
#pragma unroll
            for (int ni = 0; ni < 4; ++ni) {
                float e = __builtin_amdgcn_exp2f(acc[mi][ni][r] - Mt); // diag -> 0
                acc[mi][ni][r] = e;
                ld += e;
                ln += ((mmw >> (((mi & 1) * 4 + r) * 4 + ni)) & 1) ? e : 0.f;
            }
            int lr = mi * 16 + g * 4 + r;
            P[((wr * 2 + wc) * 16 + qq) * 64 + (lr ^ qq)] = make_float2(ld, ln);
        }
    }
    if (!diag) {
#pragma unroll
        for (int ni = 0; ni < 4; ++ni) {
            float sd = 0.f, sn = 0.f;
#pragma unroll
            for (int mi = 0; mi < 4; ++mi) {
                unsigned mmw = (mi < 2) ? mm0 : mm1;
#pragma unroll
                for (int r = 0; r < 4; ++r) {
                    float e = acc[mi][ni][r];
                    sd += e;
                    sn += ((mmw >> (((mi & 1) * 4 + r) * 4 + ni)) & 1) ? e : 0.f;
                }
            }
            sd += __shfl_xor(sd, 16, 64); sd += __shfl_xor(sd, 32, 64);
            sn += __shfl_xor(sn, 16, 64); sn += __shfl_xor(sn, 32, 64);
            if (g == 0) redC[(wc * 64 + ni * 16 + qq) * 2 + wr] = make_float2(sd, sn);
        }
    }
    __syncthreads();                               // barrier 2

    // row merge: wave 0 -> rows 0..63 (wr=0), wave 2 -> rows 64..127 (wr=1)
    if (w == 0 || w == 2) {
        const int wrh = w >> 1;
        float Ls = 0.f, Ln = 0.f;
#pragma unroll
        for (int wcx = 0; wcx < 2; ++wcx)
#pragma unroll
            for (int q = 0; q < 16; ++q) {
                float2 p = P[((wrh * 2 + wcx) * 16 + q) * 64 + (lane ^ q)];
                Ls += p.x; Ln += p.y;
            }
        part[(size_t)ct * NROW + rowTile + wrh * 64 + lane] =
            make_float4(Mt, Ls, Ln, 0.f);
    }
    // col merge (off-diag): threads 0..127
    if (!diag && tid < BM) {
        float2 a = redC[tid * 2 + 0], b = redC[tid * 2 + 1];
        part[(size_t)rt * NROW + colTile + tid] =
            make_float4(Mt, a.x + b.x, a.y + b.y, 0.f);
    }
#undef STAGE_T
}

// ---------------- combine chunks per row + final mean ----------------
__global__ __launch_bounds__(256) void k_rows(const float4* __restrict__ part,
                                              float* __restrict__ out) {
    int r = blockIdx.x * 256 + threadIdx.x;
    float M = NEG_INF, Ls = 0.f, Ln = 0.f;
    for (int ctt = 0; ctt < NT; ++ctt) {
        float4 p = part[(size_t)ctt * NROW + r];
        if (p.x > M) {
            float sc = __builtin_amdgcn_exp2f(M - p.x);
            Ls *= sc; Ln *= sc; M = p.x;
        }
        float s2 = __builtin_amdgcn_exp2f(p.x - M);
        Ls += p.y * s2;
        Ln += p.z * s2;
    }
    float v = (Ln > 0.f) ? (__builtin_amdgcn_logf(Ln) - __builtin_amdgcn_logf(Ls))
                               * 0.69314718055994530942f
                         : 0.f;
#pragma unroll
    for (int off = 32; off >= 1; off >>= 1) v += __shfl_xor(v, off, 64);
    __shared__ float sa[4];
    int w = threadIdx.x >> 6, lane = threadIdx.x & 63;
    if (lane == 0) sa[w] = v;
    __syncthreads();
    if (threadIdx.x == 0)
        atomicAdd(out, -((sa[0] + sa[1] + sa[2] + sa[3]) / (float)NROW));
}

extern "C" void kernel_launch(void* const* d_in, const int* in_sizes, int n_in,
                              void* d_out, int out_size, void* d_ws, size_t ws_size,
                              hipStream_t stream) {
    (void)in_sizes; (void)n_in; (void)out_size; (void)ws_size;
    const float* x  = (const float*)d_in[0];
    const int*   y  = (const int*)d_in[1];
    const float* Tp = (const float*)d_in[2];
    float* out = (float*)d_out;

    char* ws = (char*)d_ws;
    unsigned int*   cnt  = (unsigned int*)(ws + WS_CNT);
    float*          scal = (float*)(ws + WS_SCAL);
    unsigned short* xb   = (unsigned short*)(ws + WS_XB);
    float*          sqn  = (float*)(ws + WS_SQN);
    float*          rsum = (float*)(ws + WS_RS);
    float4*         p4   = (float4*)(ws + WS_P4);

    hipMemsetAsync(cnt, 0, 4, stream);             // last-block ticket
    hipMemsetAsync(out, 0, 4, stream);             // k_rows accumulates
    k_norm <<<NROW / 4, 256, 0, stream>>>(x, xb, sqn, rsum, cnt, scal);
    k_main <<<NBLK, 256, 0, stream>>>(xb, sqn, y, Tp, scal, p4);
    k_rows <<<NROW / 256, 256, 0, stream>>>(p4, out);
}

// Round 15
// 82.747 us; speedup vs baseline: 3.3136x; 3.3136x over previous
//
#include <hip/hip_runtime.h>

// SNN loss, MI355X. Round 15: revert to R13 (best, 83.1us) verbatim.
//  (R14's k_norm+k_prep fusion via per-block __threadfence caused repeated
//   device-scope L2 writebacks: k_norm 5->214us, VALUBusy 0.7%. Fence-per-
//   block last-block reduction is a dead end on 8-XCD CDNA4.)
//  k_norm: raw x -> bf16 (ws), per-row sqn + sum (fp32)
//  k_prep: inv_std from row sums (fp64), zeroes out[0]
//  k_main: upper-tri 128x128 MFMA tiles of x.x^T (2080 blocks), tbuf 48KB,
//          counted vmcnt(8/4/0), granule swizzle, supertile L2 decode,
//          shared-tile-max epilogue
//  k_rows: combine partials per row, block atomicAdd of -mean into out

#define NROW 8192
#define NDIM 512
#define BM   128
#define BK   32
#define NKT  (NDIM / BK)           // 16 K-tiles
#define NT   (NROW / BM)           // 64 tiles per dim
#define NBLK (NT * (NT + 1) / 2)   // 2080 upper-tri blocks
#define TILE (BM * BK)             // 4096 elements

typedef __attribute__((ext_vector_type(8))) short bf16x8;
typedef __attribute__((ext_vector_type(4))) float f32x4;

#define NEG_INF (-__builtin_inff())

// ---- workspace layout (bytes) ----
static const size_t WS_SCAL = 4096;                                // inv_std float
static const size_t WS_XB   = 8192;                                // bf16 x: 8M
static const size_t WS_SQN  = WS_XB + (size_t)NROW * NDIM * 2;     // 8192 f32
static const size_t WS_RS   = WS_SQN + (size_t)NROW * 4;           // 8192 f32 row sums
static const size_t WS_P4   = WS_RS + (size_t)NROW * 4;            // 64*8192 float4

__device__ __forceinline__ unsigned short f2bf(float f) {
    unsigned int u = __float_as_uint(f);      // finite inputs only
    u += 0x7FFFu + ((u >> 16) & 1u);          // round-to-nearest-even
    return (unsigned short)(u >> 16);
}

#define GLD_LDS16(gp, lp) __builtin_amdgcn_global_load_lds( \
    (const __attribute__((address_space(1))) unsigned int*)(gp), \
    (__attribute__((address_space(3))) unsigned int*)(lp), 16, 0, 0)

// ---------------- raw x -> bf16 + raw row sqn/sum ----------------
__global__ __launch_bounds__(256) void k_norm(const float* __restrict__ x,
                                              unsigned short* __restrict__ xb,
                                              float* __restrict__ sqn,
                                              float* __restrict__ rsum) {
    int w = threadIdx.x >> 6, lane = threadIdx.x & 63;
    int row = blockIdx.x * 4 + w;
    const float4* xr = (const float4*)(x + (size_t)row * NDIM);
    ushort4* xo = (ushort4*)(xb + (size_t)row * NDIM);
    float ss = 0.f, s1 = 0.f;
#pragma unroll
    for (int ph = 0; ph < 2; ++ph) {
        float4 v = xr[ph * 64 + lane];
        ss += v.x * v.x + v.y * v.y + v.z * v.z + v.w * v.w;
        s1 += (v.x + v.y) + (v.z + v.w);
        xo[ph * 64 + lane] = make_ushort4(f2bf(v.x), f2bf(v.y), f2bf(v.z), f2bf(v.w));
    }
#pragma unroll
    for (int off = 32; off >= 1; off >>= 1) {
        ss += __shfl_xor(ss, off, 64);
        s1 += __shfl_xor(s1, off, 64);
    }
    if (lane == 0) { sqn[row] = ss; rsum[row] = s1; }
}

// ---------------- inv_std + zero the output accumulator ----------------
__global__ __launch_bounds__(256) void k_prep(const float* __restrict__ sqn,
                                              const float* __restrict__ rsum,
                                              float* __restrict__ scal,
                                              float* __restrict__ out) {
    int t = threadIdx.x;
    double s = 0.0, ss = 0.0;
    for (int i = t; i < NROW; i += 256) { s += (double)rsum[i]; ss += (double)sqn[i]; }
#pragma unroll
    for (int off = 32; off >= 1; off >>= 1) {
        s  += __shfl_xor(s, off, 64);
        ss += __shfl_xor(ss, off, 64);
    }
    __shared__ double sa[4], sb[4];
    int w = t >> 6, lane = t & 63;
    if (lane == 0) { sa[w] = s; sb[w] = ss; }
    __syncthreads();
    if (t == 0) {
        double S = sa[0] + sa[1] + sa[2] + sa[3];
        double SS = sb[0] + sb[1] + sb[2] + sb[3];
        const double N = (double)NROW * (double)NDIM;
        double var = (SS - S * S / N) / (N - 1.0);   // ddof=1
        scal[0] = (float)(1.0 / sqrt(var));          // inv_std
        out[0] = 0.f;                                // k_rows accumulates
    }
}

// ---------------- main: upper-tri GEMM + dual-sided fused LSE ----------------
__global__ __launch_bounds__(256, 3) void k_main(const unsigned short* __restrict__ xb,
                                                 const float* __restrict__ sqn,
                                                 const int* __restrict__ y,
                                                 const float* __restrict__ Tp,
                                                 const float* __restrict__ scal,
                                                 float4* __restrict__ part) {
    // 48 KB: [buf3][A|B][128*32 bf16], granule-swizzled. Epilogue overlays:
    //   P  (float2[2 wr][2 wc][16 qq][64 rows]) at 0      (32 KB)
    //   redC (float2[128][2 wr])                at 32 KB  ( 2 KB)
    //   mxw (float[4])                          at 34 KB
    __shared__ __attribute__((aligned(16))) unsigned short lds[3][2][TILE];
    float2* P    = (float2*)&lds[0][0][0];
    float2* redC = (float2*)((char*)&lds[0][0][0] + 32768);
    float*  mxw  = (float*)((char*)&lds[0][0][0] + 34816);

    // XCD chunking (2080 = 8*260) over SUPERTILE-ordered triangle cells
    // (8x8 supertiles -> resident blocks per XCD share ~2MB of panels in L2).
    int bid = blockIdx.x;
    int L = (bid & 7) * (NBLK / 8) + (bid >> 3);
    int RT = 0;
    for (;;) { int cnt = 36 + 64 * (7 - RT); if (L < cnt) break; L -= cnt; ++RT; }
    int rt, ct;
    if (L < 36) {                    // diagonal supertile: triangular cells
        int i = 0;
        while (L >= 8 - i) { L -= 8 - i; ++i; }
        rt = RT * 8 + i; ct = RT * 8 + i + L;
    } else {                         // off-diagonal supertile: full 8x8
        L -= 36;
        int CT = RT + 1 + (L >> 6), cc = L & 63;
        rt = RT * 8 + (cc >> 3); ct = CT * 8 + (cc & 7);
    }
    const bool diag = (rt == ct);

    const int tid = threadIdx.x;
    const int w = tid >> 6, lane = tid & 63;
    const int wr = w >> 1, wc = w & 1;           // 2x2 waves, 64x64 each
    const int g = lane >> 4, qq = lane & 15;
    const int rowTile = rt * BM, colTile = ct * BM;

    // staging coords: chunk q covers rows [q*16,q*16+16); lane -> row q*16+(l>>2),
    // SOURCE granule pre-swizzled: (l&3)^((l>>3)&3) == (row>>1)&3 within chunk.
    const int q0 = w * 2, q1 = w * 2 + 1;
    const int colg = ((lane & 3) ^ ((lane >> 3) & 3)) * 8;
    const int sr = lane >> 2;
    const unsigned short* gA0 = xb + (size_t)(rowTile + q0 * 16 + sr) * NDIM + colg;
    const unsigned short* gA1 = xb + (size_t)(rowTile + q1 * 16 + sr) * NDIM + colg;
    const unsigned short* gB0 = xb + (size_t)(colTile + q0 * 16 + sr) * NDIM + colg;
    const unsigned short* gB1 = xb + (size_t)(colTile + q1 * 16 + sr) * NDIM + colg;

#define STAGE_T(buf, ke) do { \
    GLD_LDS16(gA0 + (ke), &lds[buf][0][q0 * 512]); \
    GLD_LDS16(gA1 + (ke), &lds[buf][0][q1 * 512]); \
    GLD_LDS16(gB0 + (ke), &lds[buf][1][q0 * 512]); \
    GLD_LDS16(gB1 + (ke), &lds[buf][1][q1 * 512]); } while (0)

    // swizzled read offset: granule g of row r sits at g^((r>>1)&3)
    const int kx = (g ^ ((qq >> 1) & 3)) * 8;
    const int aoff = (wr * 64 + qq) * BK + kx;     // + mi*16*BK
    const int boff = (wc * 64 + qq) * BK + kx;     // + ni*16*BK

    f32x4 acc[4][4];
    const f32x4 zero = {0.f, 0.f, 0.f, 0.f};
#pragma unroll
    for (int i = 0; i < 4; ++i)
#pragma unroll
        for (int j = 0; j < 4; ++j) acc[i][j] = zero;

    // prologue: tiles 0,1 in flight (diag stages B too: pointers coincide)
    STAGE_T(0, 0);
    STAGE_T(1, BK);

    int c = 0;
    for (int kt = 0; kt < NKT; ++kt) {
        if (kt + 2 < NKT) {
            int sb = c + 2; if (sb >= 3) sb -= 3;
            STAGE_T(sb, (kt + 2) * BK);
            asm volatile("s_waitcnt vmcnt(8)" ::: "memory");  // tile kt landed
        } else if (kt + 1 < NKT) {
            asm volatile("s_waitcnt vmcnt(4)" ::: "memory");
        } else {
            asm volatile("s_waitcnt vmcnt(0)" ::: "memory");
        }
        __builtin_amdgcn_s_barrier();                         // publish tile kt

        const unsigned short* AA = &lds[c][0][0];
        const unsigned short* BB = &lds[c][1][0];
        bf16x8 af[4], bfr[4];
#pragma unroll
        for (int mi = 0; mi < 4; ++mi)
            af[mi] = *(const bf16x8*)&AA[aoff + mi * 16 * BK];
#pragma unroll
        for (int ni = 0; ni < 4; ++ni)
            bfr[ni] = *(const bf16x8*)&BB[boff + ni * 16 * BK];
        __builtin_amdgcn_s_setprio(1);
#pragma unroll
        for (int mi = 0; mi < 4; ++mi)
#pragma unroll
            for (int ni = 0; ni < 4; ++ni)
                acc[mi][ni] = __builtin_amdgcn_mfma_f32_16x16x32_bf16(
                    af[mi], bfr[ni], acc[mi][ni], 0, 0, 0);
        __builtin_amdgcn_s_setprio(0);
        asm volatile("s_waitcnt lgkmcnt(0)" ::: "memory");    // my reads retired
        __builtin_amdgcn_s_barrier();                         // release buf c
        c += 1; if (c == 3) c = 0;
    }

    // ---- epilogue (shared tile-max) ----
    const float c2 = scal[0] * __builtin_amdgcn_exp2f(Tp[0] * 3.321928094887362f)
                             * 1.4426950408889634f;   // inv_std * 10^T * log2e
    float scol[4]; int ycol[4];
#pragma unroll
    for (int ni = 0; ni < 4; ++ni) {
        int C = colTile + wc * 64 + ni * 16 + qq;
        scol[ni] = sqn[C];
        ycol[ni] = y[C];
    }

    // pass A: acc := s2 in place; bits -> mm0/mm1; thread-local max
    unsigned mm0 = 0, mm1 = 0;
    float tmax = NEG_INF;
#pragma unroll
    for (int mi = 0; mi < 4; ++mi) {
        float srow4[4]; int yrow4[4];
#pragma unroll
        for (int r = 0; r < 4; ++r) {
            int R = rowTile + wr * 64 + mi * 16 + g * 4 + r;
            srow4[r] = sqn[R];
            yrow4[r] = y[R];
        }
#pragma unroll
        for (int r = 0; r < 4; ++r) {
            const int R = rowTile + wr * 64 + mi * 16 + g * 4 + r;
#pragma unroll
            for (int ni = 0; ni < 4; ++ni) {
                const int C = colTile + wc * 64 + ni * 16 + qq;
                float sq = fmaf(-2.f, acc[mi][ni][r], srow4[r] + scol[ni]);
                sq = fmaxf(sq, 0.f);
                float s2 = -__builtin_amdgcn_sqrtf(sq) * c2;
                if (R == C) s2 = NEG_INF;          // diagonal mask
                acc[mi][ni][r] = s2;
                tmax = fmaxf(tmax, s2);
                unsigned bit = (yrow4[r] == ycol[ni]) ? 1u : 0u;
                int idx = ((mi & 1) * 4 + r) * 4 + ni;
                if (mi < 2) mm0 |= bit << idx; else mm1 |= bit << idx;
            }
        }
    }
    // block-wide tile max Mt
#pragma unroll
    for (int off = 1; off <= 32; off <<= 1) tmax = fmaxf(tmax, __shfl_xor(tmax, off, 64));
    if (lane == 0) mxw[w] = tmax;
    __syncthreads();                               // barrier 1 (staging long dead)
    const float Mt = fmaxf(fmaxf(mxw[0], mxw[1]), fmaxf(mxw[2], mxw[3]));

    // pass B: acc := exp2(s2 - Mt); row partials -> P (float2, XOR swizzle);
    // col partials -> redC. All partials share Mt: merges are pure adds.
#pragma unroll
    for (int mi = 0; mi < 4; ++mi) {
        unsigned mmw = (mi < 2) ? mm0 : mm1;
#pragma unroll
        for (int r = 0; r < 4; ++r) {
            float ld = 0.f, ln = 0.f;
#pragma unroll
            for (int ni = 0; ni < 4; ++ni) {
                float e = __builtin_amdgcn_exp2f(acc[mi][ni][r] - Mt); // diag -> 0
                acc[mi][ni][r] = e;
                ld += e;
                ln += ((mmw >> (((mi & 1) * 4 + r) * 4 + ni)) & 1) ? e : 0.f;
            }
            int lr = mi * 16 + g * 4 + r;
            P[((wr * 2 + wc) * 16 + qq) * 64 + (lr ^ qq)] = make_float2(ld, ln);
        }
    }
    if (!diag) {
#pragma unroll
        for (int ni = 0; ni < 4; ++ni) {
            float sd = 0.f, sn = 0.f;
#pragma unroll
            for (int mi = 0; mi < 4; ++mi) {
                unsigned mmw = (mi < 2) ? mm0 : mm1;
#pragma unroll
                for (int r = 0; r < 4; ++r) {
                    float e = acc[mi][ni][r];
                    sd += e;
                    sn += ((mmw >> (((mi & 1) * 4 + r) * 4 + ni)) & 1) ? e : 0.f;
                }
            }
            sd += __shfl_xor(sd, 16, 64); sd += __shfl_xor(sd, 32, 64);
            sn += __shfl_xor(sn, 16, 64); sn += __shfl_xor(sn, 32, 64);
            if (g == 0) redC[(wc * 64 + ni * 16 + qq) * 2 + wr] = make_float2(sd, sn);
        }
    }
    __syncthreads();                               // barrier 2

    // row merge: wave 0 -> rows 0..63 (wr=0), wave 2 -> rows 64..127 (wr=1)
    if (w == 0 || w == 2) {
        const int wrh = w >> 1;
        float Ls = 0.f, Ln = 0.f;
#pragma unroll
        for (int wcx = 0; wcx < 2; ++wcx)
#pragma unroll
            for (int q = 0; q < 16; ++q) {
                float2 p = P[((wrh * 2 + wcx) * 16 + q) * 64 + (lane ^ q)];
                Ls += p.x; Ln += p.y;
            }
        part[(size_t)ct * NROW + rowTile + wrh * 64 + lane] =
            make_float4(Mt, Ls, Ln, 0.f);
    }
    // col merge (off-diag): threads 0..127
    if (!diag && tid < BM) {
        float2 a = redC[tid * 2 + 0], b = redC[tid * 2 + 1];
        part[(size_t)rt * NROW + colTile + tid] =
            make_float4(Mt, a.x + b.x, a.y + b.y, 0.f);
    }
#undef STAGE_T
}

// ---------------- combine chunks per row + final mean ----------------
__global__ __launch_bounds__(256) void k_rows(const float4* __restrict__ part,
                                              float* __restrict__ out) {
    int r = blockIdx.x * 256 + threadIdx.x;
    float M = NEG_INF, Ls = 0.f, Ln = 0.f;
    for (int ctt = 0; ctt < NT; ++ctt) {
        float4 p = part[(size_t)ctt * NROW + r];
        if (p.x > M) {
            float sc = __builtin_amdgcn_exp2f(M - p.x);
            Ls *= sc; Ln *= sc; M = p.x;
        }
        float s2 = __builtin_amdgcn_exp2f(p.x - M);
        Ls += p.y * s2;
        Ln += p.z * s2;
    }
    float v = (Ln > 0.f) ? (__builtin_amdgcn_logf(Ln) - __builtin_amdgcn_logf(Ls))
                               * 0.69314718055994530942f
                         : 0.f;
#pragma unroll
    for (int off = 32; off >= 1; off >>= 1) v += __shfl_xor(v, off, 64);
    __shared__ float sa[4];
    int w = threadIdx.x >> 6, lane = threadIdx.x & 63;
    if (lane == 0) sa[w] = v;
    __syncthreads();
    if (threadIdx.x == 0)
        atomicAdd(out, -((sa[0] + sa[1] + sa[2] + sa[3]) / (float)NROW));
}

extern "C" void kernel_launch(void* const* d_in, const int* in_sizes, int n_in,
                              void* d_out, int out_size, void* d_ws, size_t ws_size,
                              hipStream_t stream) {
    (void)in_sizes; (void)n_in; (void)out_size; (void)ws_size;
    const float* x  = (const float*)d_in[0];
    const int*   y  = (const int*)d_in[1];
    const float* Tp = (const float*)d_in[2];
    float* out = (float*)d_out;

    char* ws = (char*)d_ws;
    float*          scal = (float*)(ws + WS_SCAL);
    unsigned short* xb   = (unsigned short*)(ws + WS_XB);
    float*          sqn  = (float*)(ws + WS_SQN);
    float*          rsum = (float*)(ws + WS_RS);
    float4*         p4   = (float4*)(ws + WS_P4);

    k_norm <<<NROW / 4, 256, 0, stream>>>(x, xb, sqn, rsum);
    k_prep <<<1, 256, 0, stream>>>(sqn, rsum, scal, out);
    k_main <<<NBLK, 256, 0, stream>>>(xb, sqn, y, Tp, scal, p4);
    k_rows <<<NROW / 256, 256, 0, stream>>>(p4, out);
}